// Round 1
// baseline (410.802 us; speedup 1.0000x reference)
//
#include <hip/hip_runtime.h>
#include <stdint.h>

// Problem constants (from reference setup_inputs)
#define B_    64
#define T_    4096
#define D_    256
#define A_    50
#define APAD  64     // A padded to 4 MFMA n-tiles of 16 (cols 50..63 zeroed)
#define TB    256    // T-rows per block
#define ST    32     // T-rows per subtile (2 MFMA m-tiles)
#define NSUB  (TB / ST)
#define WT_STRIDE 264  // bf16 elems per padded W row
#define XS_STRIDE 264  // bf16 elems per padded x row (528B; row shift = 4 banks)
#define EPS_  1e-7f

// ws float layout:
//   [0      .. 16383]  num accumulator [64][256]
//   [16384 .. 16447]   den accumulator [64]
//   [16448 .. 16511]   b padded to 64
//   [16512 .. 16575]   u padded to 64
//   [16576 .. ]        Wt bf16 [64][WT_STRIDE]
#define OFF_NUM 0
#define OFF_DEN 16384
#define OFF_B   16448
#define OFF_U   16512
#define OFF_WT  16576

typedef __attribute__((ext_vector_type(8))) short short8;
typedef __attribute__((ext_vector_type(4))) float floatx4;

__device__ __forceinline__ unsigned short f32_to_bf16(float f) {
    union { float f; uint32_t u; } v; v.f = f;
    uint32_t u = v.u;
    uint32_t r = u + 0x7FFFu + ((u >> 16) & 1u);   // RNE (inputs finite)
    return (unsigned short)(r >> 16);
}

__device__ __forceinline__ float fast_tanh(float x) {
    float e2 = __expf(2.0f * x);
    return (e2 - 1.0f) * __builtin_amdgcn_rcpf(e2 + 1.0f);
}

// pack two float4 (8 consecutive cols) into 8 bf16 lanes (one short8-shaped uint4)
__device__ __forceinline__ uint4 pack8(const float4 a, const float4 b) {
    uint4 p;
    p.x = ((uint32_t)f32_to_bf16(a.y) << 16) | f32_to_bf16(a.x);
    p.y = ((uint32_t)f32_to_bf16(a.w) << 16) | f32_to_bf16(a.z);
    p.z = ((uint32_t)f32_to_bf16(b.y) << 16) | f32_to_bf16(b.x);
    p.w = ((uint32_t)f32_to_bf16(b.w) << 16) | f32_to_bf16(b.z);
    return p;
}

__device__ __forceinline__ float bf_lo(uint32_t w) { return __uint_as_float(w << 16); }
__device__ __forceinline__ float bf_hi(uint32_t w) { return __uint_as_float(w & 0xFFFF0000u); }

// ---------------- prologue: zero accumulators, pack W/b/u ----------------
__global__ void att_prologue(const float* __restrict__ W,
                             const float* __restrict__ bias,
                             const float* __restrict__ u,
                             float* __restrict__ ws) {
    int idx = blockIdx.x * blockDim.x + threadIdx.x;
    int stride = gridDim.x * blockDim.x;
    for (int i = idx; i < OFF_DEN + B_; i += stride) ws[i] = 0.0f;
    for (int i = idx; i < APAD; i += stride) {
        ws[OFF_B + i] = (i < A_) ? bias[i] : 0.0f;
        ws[OFF_U + i] = (i < A_) ? u[i]    : 0.0f;
    }
    // W [256][50] fp32 -> Wt bf16 [64][WT_STRIDE] (transposed, col-padded with 0)
    unsigned short* wt = (unsigned short*)(ws + OFF_WT);
    for (int i = idx; i < APAD * D_; i += stride) {
        int a = i >> 8;          // 0..63
        int k = i & 255;         // 0..255
        float val = (a < A_) ? W[k * A_ + a] : 0.0f;
        wt[a * WT_STRIDE + k] = f32_to_bf16(val);
    }
}

// ---------------- main fused kernel ----------------
// 4 waves/block: wave w owns n-tile w (cols 16w..16w+15), both m-tiles.
// B-fragments of W live in registers (32 VGPR/wave), loaded once.
// x tile is kept TWICE: bf16 in LDS (MFMA A-fragments) and bf16-packed in
// registers (pooling) -> phase-2 does zero LDS reads; 2 barriers/subtile.
__global__ __launch_bounds__(256, 4) void att_main(const float* __restrict__ x,
                                                   float* __restrict__ ws) {
    __shared__ __align__(16) unsigned short lds_x[ST * XS_STRIDE];  // 16896 B
    __shared__ __align__(16) float part[ST][4];

    const int tid  = threadIdx.x;
    const int wave = tid >> 6;
    const int lane = tid & 63;
    const int bb   = blockIdx.y;   // batch
    const int tblk = blockIdx.x;   // T-tile

    const float* xblk = x + ((size_t)bb * T_ + (size_t)tblk * TB) * D_;

    // ---- load this wave's B-fragments (n-tile = wave) into registers ----
    short8 bw[8];
    {
        const unsigned short* wt = (const unsigned short*)(ws + OFF_WT);
        const unsigned short* wrow = wt + (wave * 16 + (lane & 15)) * WT_STRIDE
                                        + ((lane >> 4) * 8);
        #pragma unroll
        for (int ks = 0; ks < 8; ++ks)
            bw[ks] = *(const short8*)(wrow + ks * 32);
    }

    const int c = wave * 16 + (lane & 15);
    const float b_c = ws[OFF_B + c];
    const float u_c = ws[OFF_U + c];

    // thread's x-fragment mapping: rows g+8i (i=0..3), cols 8m..8m+7
    const int g = tid >> 5;
    const int m = tid & 31;
    const int arow0 = (lane & 15) * XS_STRIDE;          // MFMA m-tile 0
    const int arow1 = (16 + (lane & 15)) * XS_STRIDE;   // MFMA m-tile 1
    const int koff  = (lane >> 4) * 8;
    const int wrow_lds = g * XS_STRIDE + m * 8;         // staging dest base

    float np[8];                 // num partials: col 8m+j over rows {g+8i}
    #pragma unroll
    for (int j = 0; j < 8; ++j) np[j] = 0.0f;
    float den_acc = 0.0f;        // only tid < ST accumulate

    uint4 rbuf[2][4];            // bf16-packed x, double-buffered (16 VGPR each)

    // ---- stage subtile 0: global -> regs -> bf16 -> (regs + LDS) ----
    {
        const float4* xg = (const float4*)xblk;
        float4 t[8];
        #pragma unroll
        for (int i = 0; i < 4; ++i) {
            t[2 * i]     = xg[2 * tid + 512 * i];
            t[2 * i + 1] = xg[2 * tid + 512 * i + 1];
        }
        #pragma unroll
        for (int i = 0; i < 4; ++i) {
            uint4 p = pack8(t[2 * i], t[2 * i + 1]);
            rbuf[0][i] = p;
            *(uint4*)&lds_x[wrow_lds + i * 8 * XS_STRIDE] = p;
        }
    }
    __syncthreads();   // tile 0 staged

    #pragma unroll
    for (int st = 0; st < NSUB; ++st) {
        const int cur = st & 1;       // compile-time after full unroll
        const int nxt = cur ^ 1;

        float4 t[8];
        const float4* xn = (const float4*)(xblk + (st + 1) * ST * D_);
        // issue first half of next subtile's loads (overlap with MFMA)
        if (st < NSUB - 1) {
            #pragma unroll
            for (int i = 0; i < 2; ++i) {
                t[2 * i]     = xn[2 * tid + 512 * i];
                t[2 * i + 1] = xn[2 * tid + 512 * i + 1];
            }
        }

        // ---- MFMA: preact[32 x 16] for this wave's n-tile ----
        floatx4 acc0 = {0.f, 0.f, 0.f, 0.f};
        floatx4 acc1 = {0.f, 0.f, 0.f, 0.f};
        #pragma unroll
        for (int ks = 0; ks < 8; ++ks) {
            short8 a0 = *(const short8*)&lds_x[arow0 + ks * 32 + koff];
            short8 a1 = *(const short8*)&lds_x[arow1 + ks * 32 + koff];
            acc0 = __builtin_amdgcn_mfma_f32_16x16x32_bf16(a0, bw[ks], acc0, 0, 0, 0);
            acc1 = __builtin_amdgcn_mfma_f32_16x16x32_bf16(a1, bw[ks], acc1, 0, 0, 0);
        }

        // second half of next subtile's loads (keeps in-flight VGPR <= 16)
        if (st < NSUB - 1) {
            #pragma unroll
            for (int i = 2; i < 4; ++i) {
                t[2 * i]     = xn[2 * tid + 512 * i];
                t[2 * i + 1] = xn[2 * tid + 512 * i + 1];
            }
        }

        // ---- logit partials: tanh(preact + b) * u, reduce over 16 cols ----
        // C/D layout: col = lane&15, row = (lane>>4)*4 + rr
        float lp0[4], lp1[4];
        #pragma unroll
        for (int rr = 0; rr < 4; ++rr) {
            float v0 = fast_tanh(acc0[rr] + b_c) * u_c;
            float v1 = fast_tanh(acc1[rr] + b_c) * u_c;
            v0 += __shfl_xor(v0, 1); v1 += __shfl_xor(v1, 1);
            v0 += __shfl_xor(v0, 2); v1 += __shfl_xor(v1, 2);
            v0 += __shfl_xor(v0, 4); v1 += __shfl_xor(v1, 4);
            v0 += __shfl_xor(v0, 8); v1 += __shfl_xor(v1, 8);
            lp0[rr] = v0; lp1[rr] = v1;
        }
        if ((lane & 15) == 0) {
            int rg = lane >> 4;
            #pragma unroll
            for (int rr = 0; rr < 4; ++rr) {
                part[rg * 4 + rr][wave]      = lp0[rr];
                part[16 + rg * 4 + rr][wave] = lp1[rr];
            }
        }
        __syncthreads();  // B2: partials ready; ALL tile-st LDS reads complete

        // ---- every thread computes ev for its own 4 rows (broadcast reads),
        //      pools from its register copy of x — zero LDS data reads ----
        #pragma unroll
        for (int i = 0; i < 4; ++i) {
            const float4 pp = *(const float4*)part[g + 8 * i];
            const float ev = __expf(pp.x + pp.y + pp.z + pp.w);
            const uint4 p = rbuf[cur][i];
            np[0] = fmaf(bf_lo(p.x), ev, np[0]);
            np[1] = fmaf(bf_hi(p.x), ev, np[1]);
            np[2] = fmaf(bf_lo(p.y), ev, np[2]);
            np[3] = fmaf(bf_hi(p.y), ev, np[3]);
            np[4] = fmaf(bf_lo(p.z), ev, np[4]);
            np[5] = fmaf(bf_hi(p.z), ev, np[5]);
            np[6] = fmaf(bf_lo(p.w), ev, np[6]);
            np[7] = fmaf(bf_hi(p.w), ev, np[7]);
        }
        if (tid < ST) {
            const float4 pp = *(const float4*)part[tid];
            den_acc += __expf(pp.x + pp.y + pp.z + pp.w);
        }

        // ---- stage subtile st+1 (safe after B2) ----
        if (st < NSUB - 1) {
            #pragma unroll
            for (int i = 0; i < 4; ++i) {
                uint4 p = pack8(t[2 * i], t[2 * i + 1]);
                rbuf[nxt][i] = p;
                *(uint4*)&lds_x[wrow_lds + i * 8 * XS_STRIDE] = p;
            }
            __syncthreads();  // B1: tile st+1 staged
        }
    }

    // ---- block-level reduction of np across the 8 row-groups ----
    // (reuse lds_x as fp32 scratch: 8 groups x 256 cols = 8 KiB <= 16.5 KiB)
    float* red = (float*)lds_x;
    *(float4*)&red[g * D_ + m * 8]     = make_float4(np[0], np[1], np[2], np[3]);
    *(float4*)&red[g * D_ + m * 8 + 4] = make_float4(np[4], np[5], np[6], np[7]);
    __syncthreads();
    float s = 0.0f;
    #pragma unroll
    for (int gg = 0; gg < 8; ++gg) s += red[gg * D_ + tid];
    atomicAdd(&ws[OFF_NUM + bb * D_ + tid], s);

    if (wave == 0) {
        float v = den_acc;  // lanes 0..31 hold partials, 32..63 hold 0
        v += __shfl_xor(v, 32);
        v += __shfl_xor(v, 16);
        v += __shfl_xor(v, 8);
        v += __shfl_xor(v, 4);
        v += __shfl_xor(v, 2);
        v += __shfl_xor(v, 1);
        if (lane == 0) atomicAdd(&ws[OFF_DEN + bb], v);
    }
}

// ---------------- epilogue: out = num / (den + eps) ----------------
__global__ void att_epilogue(const float* __restrict__ ws, float* __restrict__ out) {
    int bb = blockIdx.x;
    int d  = threadIdx.x;
    out[bb * D_ + d] = ws[OFF_NUM + bb * D_ + d] / (ws[OFF_DEN + bb] + EPS_);
}

extern "C" void kernel_launch(void* const* d_in, const int* in_sizes, int n_in,
                              void* d_out, int out_size, void* d_ws, size_t ws_size,
                              hipStream_t stream) {
    const float* x = (const float*)d_in[0];
    const float* W = (const float*)d_in[1];
    const float* b = (const float*)d_in[2];
    const float* u = (const float*)d_in[3];
    float* ws  = (float*)d_ws;
    float* out = (float*)d_out;

    att_prologue<<<64, 256, 0, stream>>>(W, b, u, ws);
    att_main<<<dim3(T_ / TB, B_), 256, 0, stream>>>(x, ws);
    att_epilogue<<<B_, 256, 0, stream>>>(ws, out);
}